// Round 7
// baseline (905.956 us; speedup 1.0000x reference)
//
#include <hip/hip_runtime.h>
#include <stdint.h>

#define KTAPS 8
#define C 32
#define CAPR 16      // per-row bucket capacity; lambda=4, P(Poisson(4)>16)~6e-7/row
#define OMAX 8192

typedef float f32x4 __attribute__((ext_vector_type(4)));

// ---------------------------------------------------------------------------
// init: zero row counters + ocount (+pad).
// ---------------------------------------------------------------------------
__global__ __launch_bounds__(256) void init_kernel(
    unsigned int* __restrict__ cnt, int n4) {
  int i = blockIdx.x * 256 + threadIdx.x;
  if (i < n4) ((uint4*)cnt)[i] = make_uint4(0u, 0u, 0u, 0u);
}

// ---------------------------------------------------------------------------
// phase A: bin rules by OUTPUT ROW. Entry = (k<<21)|ri (24 bits; ri<2^21).
// Thread-per-rule, coalesced rule reads, k block-uniform. 1.6M counter
// atomics; 4B entry scatter carries the known ~90MB tail-line write-amp
// (round-0 measured) -- acceptable, it replaces the 205MB contrib stream
// plus its random reread entirely.
// ---------------------------------------------------------------------------
__global__ __launch_bounds__(256) void bin_row_kernel(
    const int* __restrict__ rules_in, const int* __restrict__ rules_out,
    unsigned int* __restrict__ cnt, unsigned int* __restrict__ bidx,
    uint4* __restrict__ oflow, unsigned int* __restrict__ ocount, int R) {
  const int k = blockIdx.y;
  const int r = blockIdx.x * 256 + threadIdx.x;
  if (r >= R) return;
  const unsigned int ri = (unsigned int)rules_in[(size_t)k * R + r];
  const unsigned int ro = (unsigned int)rules_out[(size_t)k * R + r];
  const unsigned int slot = atomicAdd(cnt + ro, 1u);
  if (slot < (unsigned)CAPR) {
    bidx[(size_t)ro * CAPR + slot] = ((unsigned)k << 21) | ri;
  } else {
    unsigned int j = atomicAdd(ocount, 1u);
    if (j < (unsigned)OMAX) oflow[j] = make_uint4(ro, ri, (unsigned)k, 0u);
  }
}

// ---------------------------------------------------------------------------
// phase B: one 32-lane group OWNS one output row (lane = co). No barriers,
// no LDS, no atomics; waves retire independently (kills round-5's convoy).
// Per contribution c (broadcast (ri,k) via shfl from lane c):
//   - input row via 8 uniform-address float4 loads (L1/L3 broadcast; each
//     input line fetched from memory exactly once globally -- rules_in is
//     a permutation)
//   - weights w[k][ci][lane]: lane-coalesced 128B lines, 8KB table L1-hot
//   - 32 fmaf into 4 split accumulators (breaks the dependent chain)
// Row written exactly once: pure coalesced store, bias in-register.
// ---------------------------------------------------------------------------
__global__ __launch_bounds__(256) void row_gemv_kernel(
    const unsigned int* __restrict__ cnt, const unsigned int* __restrict__ bidx,
    const float* __restrict__ in, const float* __restrict__ w,
    const float* __restrict__ bias, float* __restrict__ out, int n_out) {
  const int g    = threadIdx.x >> 5;
  const int lane = threadIdx.x & 31;
  const int row  = blockIdx.x * 8 + g;
  if (row >= n_out) return;

  unsigned int n = cnt[row];
  if (n > (unsigned)CAPR) n = CAPR;

  // 16 entries live in lanes 0-15 (one 64B line per group)
  const unsigned int ent = bidx[(size_t)row * CAPR + (lane & 15)];

  float acc0 = 0.f, acc1 = 0.f, acc2 = 0.f, acc3 = 0.f;

  for (unsigned int c = 0; c < n; ++c) {
    const unsigned int ec = (unsigned int)__shfl((int)ent, (int)c, 32);
    const unsigned int ri = ec & 0x1FFFFFu;
    const unsigned int k  = ec >> 21;

    const f32x4* ap = (const f32x4*)(in + (size_t)ri * C);
    const float* wp = w + k * (C * C) + lane;

    // 8 independent uniform-address 16B loads -- row in registers
    f32x4 a0 = ap[0], a1 = ap[1], a2 = ap[2], a3 = ap[3];
    f32x4 a4 = ap[4], a5 = ap[5], a6 = ap[6], a7 = ap[7];

    acc0 = fmaf(a0.x, wp[ 0 * C], acc0); acc1 = fmaf(a0.y, wp[ 1 * C], acc1);
    acc2 = fmaf(a0.z, wp[ 2 * C], acc2); acc3 = fmaf(a0.w, wp[ 3 * C], acc3);
    acc0 = fmaf(a1.x, wp[ 4 * C], acc0); acc1 = fmaf(a1.y, wp[ 5 * C], acc1);
    acc2 = fmaf(a1.z, wp[ 6 * C], acc2); acc3 = fmaf(a1.w, wp[ 7 * C], acc3);
    acc0 = fmaf(a2.x, wp[ 8 * C], acc0); acc1 = fmaf(a2.y, wp[ 9 * C], acc1);
    acc2 = fmaf(a2.z, wp[10 * C], acc2); acc3 = fmaf(a2.w, wp[11 * C], acc3);
    acc0 = fmaf(a3.x, wp[12 * C], acc0); acc1 = fmaf(a3.y, wp[13 * C], acc1);
    acc2 = fmaf(a3.z, wp[14 * C], acc2); acc3 = fmaf(a3.w, wp[15 * C], acc3);
    acc0 = fmaf(a4.x, wp[16 * C], acc0); acc1 = fmaf(a4.y, wp[17 * C], acc1);
    acc2 = fmaf(a4.z, wp[18 * C], acc2); acc3 = fmaf(a4.w, wp[19 * C], acc3);
    acc0 = fmaf(a5.x, wp[20 * C], acc0); acc1 = fmaf(a5.y, wp[21 * C], acc1);
    acc2 = fmaf(a5.z, wp[22 * C], acc2); acc3 = fmaf(a5.w, wp[23 * C], acc3);
    acc0 = fmaf(a6.x, wp[24 * C], acc0); acc1 = fmaf(a6.y, wp[25 * C], acc1);
    acc2 = fmaf(a6.z, wp[26 * C], acc2); acc3 = fmaf(a6.w, wp[27 * C], acc3);
    acc0 = fmaf(a7.x, wp[28 * C], acc0); acc1 = fmaf(a7.y, wp[29 * C], acc1);
    acc2 = fmaf(a7.z, wp[30 * C], acc2); acc3 = fmaf(a7.w, wp[31 * C], acc3);
  }

  out[(size_t)row * C + lane] = ((acc0 + acc1) + (acc2 + acc3)) + bias[lane];
}

// ---------------------------------------------------------------------------
// overflow fixup (expected ~0 entries): group-per-entry, lane=co.
// ---------------------------------------------------------------------------
__global__ __launch_bounds__(256) void oflow_kernel(
    const uint4* __restrict__ oflow, const unsigned int* __restrict__ ocount,
    const float* __restrict__ in, const float* __restrict__ w,
    float* __restrict__ out) {
  const int g  = threadIdx.x >> 5;
  const int co = threadIdx.x & 31;
  unsigned int n = *ocount;
  if (n > (unsigned)OMAX) n = (unsigned)OMAX;
  for (unsigned int e = g; e < n; e += 8) {
    const uint4 ent = oflow[e];      // (ro, ri, k)
    const float* ap = in + (size_t)ent.y * C;
    const float* wk = w + ent.z * (C * C);
    float acc = 0.f;
#pragma unroll
    for (int ci = 0; ci < C; ++ci) acc = fmaf(ap[ci], wk[ci * C + co], acc);
    unsafeAtomicAdd(out + (size_t)ent.x * C + co, acc);
  }
}

// ---------------------------------------------------------------------------
// fallback (workspace too small): round-1 fused atomic path (proven 407us).
// ---------------------------------------------------------------------------
#define LDSS 33
__global__ __launch_bounds__(256) void bias_init_kernel(
    float* __restrict__ out, const float* __restrict__ bias, int n4) {
  int idx = blockIdx.x * 256 + threadIdx.x;
  if (idx >= n4) return;
  ((float4*)out)[idx] = ((const float4*)bias)[idx & 7];
}

__global__ __launch_bounds__(256) void fused_scatter_kernel(
    const float* __restrict__ in, const float* __restrict__ w,
    const int* __restrict__ rules_in, const int* __restrict__ rules_out,
    float* __restrict__ out, int R) {
  __shared__ float cbuf[256 * LDSS];
  __shared__ int   robuf[256];
  const int k = blockIdx.y, tid = threadIdx.x;
  const int r = blockIdx.x * 256 + tid;
  const int lane = tid & 63, wbase = tid & ~63;
  if (blockIdx.x * 256 + wbase >= R) return;
  const bool valid = (r < R);
  const int rc = valid ? r : (R - 1);
  const int ri = rules_in[(size_t)k * R + rc];
  const int ro = valid ? rules_out[(size_t)k * R + rc] : -1;
  robuf[tid] = ro;
  const float4* rowp = (const float4*)(in + (size_t)ri * C);
  float4 av[8];
#pragma unroll
  for (int j = 0; j < 8; ++j) av[j] = rowp[j];
  float a[C];
#pragma unroll
  for (int j = 0; j < 8; ++j) {
    a[4 * j + 0] = av[j].x; a[4 * j + 1] = av[j].y;
    a[4 * j + 2] = av[j].z; a[4 * j + 3] = av[j].w;
  }
  const float* wk = w + k * (C * C);
  float acc[C];
#pragma unroll
  for (int co = 0; co < C; ++co) acc[co] = a[0] * wk[co];
#pragma unroll
  for (int ci = 1; ci < C; ++ci)
#pragma unroll
    for (int co = 0; co < C; ++co)
      acc[co] = fmaf(a[ci], wk[ci * C + co], acc[co]);
  float* myrow = cbuf + tid * LDSS;
#pragma unroll
  for (int co = 0; co < C; ++co) myrow[co] = acc[co];
  const int co = lane & 31, half = lane >> 5;
#pragma unroll
  for (int j = 0; j < 32; ++j) {
    const int rl  = wbase + 2 * j + half;
    const int rol = robuf[rl];
    const float v = cbuf[rl * LDSS + co];
    if (rol >= 0) unsafeAtomicAdd(out + (size_t)rol * C + co, v);
  }
}

extern "C" void kernel_launch(void* const* d_in, const int* in_sizes, int n_in,
                              void* d_out, int out_size, void* d_ws, size_t ws_size,
                              hipStream_t stream) {
  const float* in_features = (const float*)d_in[0];
  const float* weight      = (const float*)d_in[1];
  const float* bias        = (const float*)d_in[2];
  const int*   rules_in    = (const int*)d_in[3];
  const int*   rules_out   = (const int*)d_in[4];

  const int R     = in_sizes[3] / KTAPS;   // 200000
  const int n_out = out_size / C;          // 400000
  float* out = (float*)d_out;

  // workspace layout (16B-aligned sections)
  const size_t n_cnt   = ((size_t)n_out + 4 + 3) & ~(size_t)3;   // counters + ocount
  const size_t cnt_b   = n_cnt * sizeof(unsigned int);           // ~1.6 MB
  const size_t bidx_b  = (size_t)n_out * CAPR * sizeof(unsigned int); // 25.6 MB
  const size_t oflow_b = (size_t)OMAX * sizeof(uint4);           // 128 KB

  if (ws_size >= cnt_b + bidx_b + oflow_b) {
    unsigned int* cnt    = (unsigned int*)d_ws;
    unsigned int* ocount = cnt + n_out;
    unsigned int* bidx   = (unsigned int*)((char*)d_ws + cnt_b);
    uint4*        oflow  = (uint4*)((char*)d_ws + cnt_b + bidx_b);

    const int n4 = (int)(n_cnt / 4);
    init_kernel<<<(n4 + 255) / 256, 256, 0, stream>>>(cnt, n4);

    dim3 gridA((R + 255) / 256, KTAPS);
    bin_row_kernel<<<gridA, 256, 0, stream>>>(rules_in, rules_out, cnt, bidx,
                                              oflow, ocount, R);

    row_gemv_kernel<<<(n_out + 7) / 8, 256, 0, stream>>>(cnt, bidx, in_features,
                                                         weight, bias, out, n_out);

    oflow_kernel<<<1, 256, 0, stream>>>(oflow, ocount, in_features, weight, out);
  } else {
    const int n_out4 = out_size / 4;
    bias_init_kernel<<<(n_out4 + 255) / 256, 256, 0, stream>>>(out, bias, n_out4);
    dim3 grid((R + 255) / 256, KTAPS);
    fused_scatter_kernel<<<grid, 256, 0, stream>>>(in_features, weight, rules_in,
                                                   rules_out, out, R);
  }
}